// Round 1
// baseline (572.764 us; speedup 1.0000x reference)
//
#include <hip/hip_runtime.h>

// Involution2d fused kernel, fp32 baseline.
// Layout: one block = one (batch, 8x8 spatial tile). 256 threads.
// Phase 1: r[64 ch][64 px] = ReLU(BN(w_reduce @ x_tile)) in LDS.
// Phase 2: per group g (16): stage w_span slice + x halo tile, compute
//          dynamic kernel w[49][64 px], apply involution, write out.

namespace {
constexpr int Bn = 16, Cn = 256, Hn = 64, Wn = 64;
constexpr int Gn = 16, CGn = 16, CRn = 64;
constexpr int Kn = 7, PADn = 3, KKn = 49;
constexpr int TH = 8, TW = 8, TP = 64;          // tile pixels
constexpr int HALO = TH + 2 * PADn;             // 14
constexpr int HALOSZ = HALO * HALO;             // 196
}

__global__ __launch_bounds__(256, 2) void invol_fused(
    const float* __restrict__ x, const float* __restrict__ w_reduce,
    const float* __restrict__ w_span, const float* __restrict__ bn_gamma,
    const float* __restrict__ bn_beta, const float* __restrict__ bn_mean,
    const float* __restrict__ bn_var, float* __restrict__ out)
{
    __shared__ float s_r[CRn * TP];       // r[o][p]  (16 KB), persists all phases
    __shared__ float s_buf[3 * KKn * 64]; // 9408 floats, unioned between phases
    __shared__ float s_scale[CRn], s_shift[CRn];

    const int t  = threadIdx.x;
    const int w0 = blockIdx.x * TW;
    const int h0 = blockIdx.y * TH;
    const int b  = blockIdx.z;

    if (t < CRn) {
        float sc = bn_gamma[t] * rsqrtf(bn_var[t] + 1e-5f);
        s_scale[t] = sc;
        s_shift[t] = bn_beta[t] - bn_mean[t] * sc;
    }

    const int p  = t & 63;   // pixel in tile (lane id -> conflict-free LDS)
    const int q  = t >> 6;   // wave id 0..3 (wave-uniform -> LDS broadcast)
    const int py = p >> 3, px = p & 7;
    const long xbase = (long)b * Cn * Hn * Wn;

    // ---------------- Phase 1: r = ReLU(BN(w_reduce @ x)) ----------------
    float acc[16];
#pragma unroll
    for (int j = 0; j < 16; ++j) acc[j] = 0.f;

    float* xs = s_buf;          // [64 c][64 p] chunk of x
    float* wr = s_buf + 4096;   // [64 o][64 c] chunk of w_reduce

    for (int cc = 0; cc < Cn; cc += 64) {
        __syncthreads();
#pragma unroll
        for (int i = 0; i < 16; ++i) {
            int idx = t + i * 256;
            int c = idx >> 6, pp = idx & 63;
            xs[idx] = x[xbase + (long)(cc + c) * (Hn * Wn)
                        + (h0 + (pp >> 3)) * Wn + (w0 + (pp & 7))];
        }
#pragma unroll
        for (int i = 0; i < 16; ++i) {
            int idx = t + i * 256;
            int o = idx >> 6, c = idx & 63;
            wr[idx] = w_reduce[o * Cn + cc + c];
        }
        __syncthreads();
        // register-blocked: 1 xs read + 16 broadcast wr reads per c
        for (int c = 0; c < 64; ++c) {
            float xv = xs[c * 64 + p];
#pragma unroll
            for (int j = 0; j < 16; ++j)
                acc[j] = fmaf(wr[(q + j * 4) * 64 + c], xv, acc[j]);
        }
    }
    __syncthreads();
#pragma unroll
    for (int j = 0; j < 16; ++j) {
        int o = q + j * 4;
        float v = fmaf(acc[j], s_scale[o], s_shift[o]);
        s_r[o * 64 + p] = fmaxf(v, 0.f);
    }

    // ---------------- Phase 2: per-group dynamic kernel + involution -----
    float* wspan_s = s_buf;                // [49 k][64 o]
    float* s_w     = s_buf + KKn * 64;     // [49 k][64 p]
    float* xh      = s_buf + 2 * KKn * 64; // [16 cg][14][14]

    for (int g = 0; g < Gn; ++g) {
        __syncthreads();  // previous group's buffers fully consumed
        const float* wsg = w_span + g * KKn * CRn;  // contiguous slice
        for (int idx = t; idx < KKn * CRn; idx += 256)
            wspan_s[idx] = wsg[idx];
        for (int idx = t; idx < CGn * HALOSZ; idx += 256) {
            int cg = idx / HALOSZ, rem = idx % HALOSZ;
            int iy = rem / HALO, ix = rem % HALO;
            int gy = h0 + iy - PADn, gx = w0 + ix - PADn;
            float v = 0.f;
            if (gy >= 0 && gy < Hn && gx >= 0 && gx < Wn)
                v = x[xbase + (long)(g * CGn + cg) * (Hn * Wn) + gy * Wn + gx];
            xh[idx] = v;
        }
        __syncthreads();

        // w[k][p] = sum_o wspan[k][o] * r[o][p]; register-block 13 k per thread
        {
            float a[13];
#pragma unroll
            for (int kk = 0; kk < 13; ++kk) a[kk] = 0.f;
            for (int o = 0; o < CRn; ++o) {
                float rv = s_r[o * 64 + p];
#pragma unroll
                for (int kk = 0; kk < 13; ++kk) {
                    int k = q + kk * 4;  // k<52; reads past wspan stay in s_buf (finite)
                    a[kk] = fmaf(wspan_s[k * 64 + o], rv, a[kk]);
                }
            }
            __syncthreads();  // done reading previous s_w (none) / ordering
#pragma unroll
            for (int kk = 0; kk < 13; ++kk) {
                int k = q + kk * 4;
                if (k < KKn) s_w[k * 64 + p] = a[kk];
            }
        }
        __syncthreads();

        // involution: out[cg][p] = sum_k w[k][p] * xh[cg][py+i][px+j]
        float oacc[4];
#pragma unroll
        for (int jj = 0; jj < 4; ++jj) oacc[jj] = 0.f;
#pragma unroll
        for (int i = 0; i < Kn; ++i) {
#pragma unroll
            for (int jx = 0; jx < Kn; ++jx) {
                float wv = s_w[(i * Kn + jx) * 64 + p];
#pragma unroll
                for (int jj = 0; jj < 4; ++jj) {
                    int cg = q + jj * 4;
                    oacc[jj] = fmaf(wv, xh[cg * HALOSZ + (py + i) * HALO + (px + jx)], oacc[jj]);
                }
            }
        }
#pragma unroll
        for (int jj = 0; jj < 4; ++jj) {
            int cg = q + jj * 4;
            out[xbase + (long)(g * CGn + cg) * (Hn * Wn) + (h0 + py) * Wn + (w0 + px)] = oacc[jj];
        }
    }
}

extern "C" void kernel_launch(void* const* d_in, const int* in_sizes, int n_in,
                              void* d_out, int out_size, void* d_ws, size_t ws_size,
                              hipStream_t stream) {
    const float* x        = (const float*)d_in[0];
    const float* w_reduce = (const float*)d_in[1];
    const float* w_span   = (const float*)d_in[2];
    const float* bn_gamma = (const float*)d_in[3];
    const float* bn_beta  = (const float*)d_in[4];
    const float* bn_mean  = (const float*)d_in[5];
    const float* bn_var   = (const float*)d_in[6];
    float* outp = (float*)d_out;

    dim3 grid(Wn / TW, Hn / TH, Bn);  // 8 x 8 x 16 = 1024 blocks
    invol_fused<<<grid, 256, 0, stream>>>(x, w_reduce, w_span, bn_gamma,
                                          bn_beta, bn_mean, bn_var, outp);
}

// Round 2
// 301.970 us; speedup vs baseline: 1.8968x; 1.8968x over previous
//
#include <hip/hip_runtime.h>

// Involution2d fused, MFMA version.
// Block = one (batch, 8x8 tile), 256 threads / 4 waves.
// Phase 1: rT[p][o] = bf16(ReLU(BN(w_reduce @ x_tile)))  via mfma 16x16x32 bf16
// Phase 2 per group g: s_ws[k][o] staged; w = ws @ r via MFMA -> s_wT[k][p] bf16;
//                      involution vs xh (8 cg planes x 2 passes, stride-24 rows).

typedef __attribute__((ext_vector_type(8))) short bf16x8;
typedef __attribute__((ext_vector_type(4))) float f32x4;

namespace {
constexpr int Cn = 256, Hn = 64, Wn = 64, HWn = 4096;
constexpr int Gn = 16, CGn = 16, CRn = 64;
constexpr int Kn = 7, PADn = 3, KKn = 49;
constexpr int TH = 8, TW = 8;
constexpr int LD = 72, LDW = 36;       // bf16 row stride / dword row stride
constexpr int XROW = 24, XPLANE = 14 * 24;  // xh padded row, plane (stride-24 -> 2-way free)
constexpr int HALO = 14, HALOSZ = 196;
}

__device__ __forceinline__ unsigned short bf16rne(float f) {
  unsigned u = __float_as_uint(f);
  u += 0x7fffu + ((u >> 16) & 1u);
  return (unsigned short)(u >> 16);
}
__device__ __forceinline__ unsigned packbf2(float a, float b) {
  return (unsigned)bf16rne(a) | ((unsigned)bf16rne(b) << 16);
}

__global__ __launch_bounds__(256, 4) void invol_fused(
    const float* __restrict__ x, const float* __restrict__ w_reduce,
    const float* __restrict__ w_span, const float* __restrict__ bn_gamma,
    const float* __restrict__ bn_beta, const float* __restrict__ bn_mean,
    const float* __restrict__ bn_var, float* __restrict__ out)
{
  __shared__ __align__(16) unsigned short s_rT[64 * LD];  // rT[p][o] bf16, 9.2 KB
  __shared__ __align__(16) unsigned short s_a [64 * LD];  // ph1: wr[o][c]; ph2: ws[k][o]
  __shared__ __align__(16) unsigned short s_b [64 * LD];  // ph1: xT[p][c]; ph2: wT[k][p]
  __shared__ __align__(16) float s_xh[8 * XPLANE];        // 8 halo planes, 10.5 KB

  const int t = threadIdx.x;
  const int lane = t & 63, q = t >> 6;
  const int m16 = lane & 15, quad = lane >> 4;
  const int py = lane >> 3, px = lane & 7;
  const int w0 = blockIdx.x * TW, h0 = blockIdx.y * TH;
  const int b = blockIdx.z;
  const long xbase = (long)b * Cn * HWn;

  // BN constants for this lane's 4 phase-1 D rows (o = q*16 + quad*4 + r)
  float bsc[4], bsh[4];
  {
    int ob = q * 16 + quad * 4;
#pragma unroll
    for (int r = 0; r < 4; ++r) {
      float sc = bn_gamma[ob + r] * rsqrtf(bn_var[ob + r] + 1e-5f);
      bsc[r] = sc;
      bsh[r] = bn_beta[ob + r] - bn_mean[ob + r] * sc;
    }
  }

  // ---------------- Phase 1: rT = bf16(ReLU(BN(w_reduce @ x))) ----------------
  f32x4 acc0, acc1, acc2, acc3;
  acc0 = acc1 = acc2 = acc3 = (f32x4){0.f, 0.f, 0.f, 0.f};

  for (int cc = 0; cc < Cn; cc += 64) {
    __syncthreads();
    // stage s_a = w_reduce[o][cc+..] -> bf16 [o][LD]  (coalesced float2 rows)
#pragma unroll
    for (int it = 0; it < 8; ++it) {
      int idx = t + it * 256;
      int o = idx >> 5, cp = idx & 31;
      float2 v = *(const float2*)(w_reduce + o * Cn + cc + cp * 2);
      ((unsigned*)s_a)[o * LDW + cp] = packbf2(v.x, v.y);
    }
    // stage s_b = xT[p][c] bf16 (transpose: 2 strided global reads -> 1 packed write)
#pragma unroll
    for (int it = 0; it < 8; ++it) {
      int idx = t + it * 256;
      int pp = idx & 63, cp = idx >> 6;
      const float* gp = x + xbase + (long)(cc + cp * 2) * HWn
                        + (h0 + (pp >> 3)) * Wn + (w0 + (pp & 7));
      ((unsigned*)s_b)[pp * LDW + cp] = packbf2(gp[0], gp[HWn]);
    }
    __syncthreads();
    // wave q -> o-tile q; 4 p-tiles; 2 K-steps of 32
#pragma unroll
    for (int s = 0; s < 2; ++s) {
      bf16x8 af = *(const bf16x8*)(s_a + (q * 16 + m16) * LD + s * 32 + quad * 8);
      bf16x8 b0 = *(const bf16x8*)(s_b + (m16)      * LD + s * 32 + quad * 8);
      bf16x8 b1 = *(const bf16x8*)(s_b + (16 + m16) * LD + s * 32 + quad * 8);
      bf16x8 b2 = *(const bf16x8*)(s_b + (32 + m16) * LD + s * 32 + quad * 8);
      bf16x8 b3 = *(const bf16x8*)(s_b + (48 + m16) * LD + s * 32 + quad * 8);
      acc0 = __builtin_amdgcn_mfma_f32_16x16x32_bf16(af, b0, acc0, 0, 0, 0);
      acc1 = __builtin_amdgcn_mfma_f32_16x16x32_bf16(af, b1, acc1, 0, 0, 0);
      acc2 = __builtin_amdgcn_mfma_f32_16x16x32_bf16(af, b2, acc2, 0, 0, 0);
      acc3 = __builtin_amdgcn_mfma_f32_16x16x32_bf16(af, b3, acc3, 0, 0, 0);
    }
  }
  // epilogue: BN + ReLU, write rT[p][o] packed bf16 pairs (o pairs: q*8+quad*2+{0,1})
  {
    f32x4 aa[4] = {acc0, acc1, acc2, acc3};
#pragma unroll
    for (int pt = 0; pt < 4; ++pt) {
      int pp = pt * 16 + m16;
      float v0 = fmaxf(fmaf(aa[pt][0], bsc[0], bsh[0]), 0.f);
      float v1 = fmaxf(fmaf(aa[pt][1], bsc[1], bsh[1]), 0.f);
      float v2 = fmaxf(fmaf(aa[pt][2], bsc[2], bsh[2]), 0.f);
      float v3 = fmaxf(fmaf(aa[pt][3], bsc[3], bsh[3]), 0.f);
      ((unsigned*)s_rT)[pp * LDW + q * 8 + quad * 2 + 0] = packbf2(v0, v1);
      ((unsigned*)s_rT)[pp * LDW + q * 8 + quad * 2 + 1] = packbf2(v2, v3);
    }
  }

  // ---------------- Phase 2: per-group kernel-gen (MFMA) + involution ----------------
  const int pix = (h0 + py) * Wn + (w0 + px);

  for (int g = 0; g < Gn; ++g) {
    __syncthreads();  // prior reads of s_a/s_b/s_xh complete; rT visible after next barrier
    // stage s_a = w_span slice [k][o] bf16, zero rows k>=49
#pragma unroll
    for (int it = 0; it < 8; ++it) {
      int idx = t + it * 256;
      int k = idx >> 5, op = idx & 31;
      unsigned pv = 0u;
      if (k < KKn) {
        float2 v = *(const float2*)(w_span + (long)(g * KKn + k) * CRn + op * 2);
        pv = packbf2(v.x, v.y);
      }
      ((unsigned*)s_a)[k * LDW + op] = pv;
    }
    // stage xh planes cg 0..7 (stride-24 rows)
    for (int idx = t; idx < 8 * HALOSZ; idx += 256) {
      int c8 = idx / HALOSZ, rem = idx - c8 * HALOSZ;
      int iy = rem / HALO, ix = rem - iy * HALO;
      int gy = h0 + iy - PADn, gx = w0 + ix - PADn;
      float v = 0.f;
      if ((unsigned)gy < (unsigned)Hn && (unsigned)gx < (unsigned)Wn)
        v = x[xbase + (long)(g * CGn + c8) * HWn + gy * Wn + gx];
      s_xh[c8 * XPLANE + iy * XROW + ix] = v;
    }
    __syncthreads();
    // kernel-gen: wave q -> k-tile q; D[k][p] = ws @ r
    f32x4 wa0, wa1, wa2, wa3;
    wa0 = wa1 = wa2 = wa3 = (f32x4){0.f, 0.f, 0.f, 0.f};
#pragma unroll
    for (int s = 0; s < 2; ++s) {
      bf16x8 af = *(const bf16x8*)(s_a + (q * 16 + m16) * LD + s * 32 + quad * 8);
      bf16x8 b0 = *(const bf16x8*)(s_rT + (m16)      * LD + s * 32 + quad * 8);
      bf16x8 b1 = *(const bf16x8*)(s_rT + (16 + m16) * LD + s * 32 + quad * 8);
      bf16x8 b2 = *(const bf16x8*)(s_rT + (32 + m16) * LD + s * 32 + quad * 8);
      bf16x8 b3 = *(const bf16x8*)(s_rT + (48 + m16) * LD + s * 32 + quad * 8);
      wa0 = __builtin_amdgcn_mfma_f32_16x16x32_bf16(af, b0, wa0, 0, 0, 0);
      wa1 = __builtin_amdgcn_mfma_f32_16x16x32_bf16(af, b1, wa1, 0, 0, 0);
      wa2 = __builtin_amdgcn_mfma_f32_16x16x32_bf16(af, b2, wa2, 0, 0, 0);
      wa3 = __builtin_amdgcn_mfma_f32_16x16x32_bf16(af, b3, wa3, 0, 0, 0);
    }
    // write s_wT[k][p] bf16 (u16 scalar writes; lanes share dwords -> ~2-way)
    {
      unsigned short* swt = s_b;
      int kb = q * 16 + quad * 4;
      f32x4 ww[4] = {wa0, wa1, wa2, wa3};
#pragma unroll
      for (int pt = 0; pt < 4; ++pt) {
        int pp = pt * 16 + m16;
        swt[(kb + 0) * LD + pp] = bf16rne(ww[pt][0]);
        swt[(kb + 1) * LD + pp] = bf16rne(ww[pt][1]);
        swt[(kb + 2) * LD + pp] = bf16rne(ww[pt][2]);
        swt[(kb + 3) * LD + pp] = bf16rne(ww[pt][3]);
      }
    }
    __syncthreads();
    // involution: 2 passes of 8 cg planes; lane = pixel, planes q and q+4
#pragma unroll 1
    for (int half = 0; half < 2; ++half) {
      if (half) {
        __syncthreads();
        for (int idx = t; idx < 8 * HALOSZ; idx += 256) {
          int c8 = idx / HALOSZ, rem = idx - c8 * HALOSZ;
          int iy = rem / HALO, ix = rem - iy * HALO;
          int gy = h0 + iy - PADn, gx = w0 + ix - PADn;
          float v = 0.f;
          if ((unsigned)gy < (unsigned)Hn && (unsigned)gx < (unsigned)Wn)
            v = x[xbase + (long)(g * CGn + 8 + c8) * HWn + gy * Wn + gx];
          s_xh[c8 * XPLANE + iy * XROW + ix] = v;
        }
        __syncthreads();
      }
      float o0 = 0.f, o1 = 0.f;
      const unsigned short* swt = s_b;
#pragma unroll
      for (int i = 0; i < Kn; ++i) {
#pragma unroll
        for (int jx = 0; jx < Kn; ++jx) {
          float wv = __uint_as_float((unsigned)swt[(i * Kn + jx) * LD + lane] << 16);
          int xo = (py + i) * XROW + (px + jx);
          o0 = fmaf(wv, s_xh[q * XPLANE + xo], o0);
          o1 = fmaf(wv, s_xh[(q + 4) * XPLANE + xo], o1);
        }
      }
      int ch = g * CGn + half * 8;
      out[xbase + (long)(ch + q)     * HWn + pix] = o0;
      out[xbase + (long)(ch + q + 4) * HWn + pix] = o1;
    }
  }
}

extern "C" void kernel_launch(void* const* d_in, const int* in_sizes, int n_in,
                              void* d_out, int out_size, void* d_ws, size_t ws_size,
                              hipStream_t stream) {
  const float* x        = (const float*)d_in[0];
  const float* w_reduce = (const float*)d_in[1];
  const float* w_span   = (const float*)d_in[2];
  const float* bn_gamma = (const float*)d_in[3];
  const float* bn_beta  = (const float*)d_in[4];
  const float* bn_mean  = (const float*)d_in[5];
  const float* bn_var   = (const float*)d_in[6];
  float* outp = (float*)d_out;

  dim3 grid(Wn / TW, Hn / TH, 16);  // 8 x 8 x 16 = 1024 blocks
  invol_fused<<<grid, 256, 0, stream>>>(x, w_reduce, w_span, bn_gamma,
                                        bn_beta, bn_mean, bn_var, outp);
}

// Round 3
// 300.733 us; speedup vs baseline: 1.9046x; 1.0041x over previous
//
#include <hip/hip_runtime.h>

// Involution2d fused, MFMA + sliding-window involution.
// Block = (batch, 8-row x 16-col tile), 256 threads / 4 waves, 2 blocks/CU.
// Phase 1: rT[p][o] = bf16(ReLU(BN(w_reduce @ x)))   via mfma 16x16x32 bf16
// Phase 2 per group: kernel-gen MFMA -> s_w[k][p] fp32; involution with
//   4 output px/lane (b128 weight + xh reads), 2 cg planes/lane.

typedef __attribute__((ext_vector_type(8))) short bf16x8;
typedef __attribute__((ext_vector_type(4))) float f32x4;

namespace {
constexpr int Cn = 256, Hn = 64, Wn = 64, HWn = 4096;
constexpr int Gn = 16, CGn = 16, CRn = 64;
constexpr int Kn = 7, PADn = 3, KKn = 49;
constexpr int TH = 8, TW = 16, TP = 128;   // tile pixels
constexpr int LD = 72, LDW = 36;           // bf16 row stride (64 + 8 pad) / dwords
constexpr int WLD = 132;                   // s_w fp32 row stride (128 px + 4 pad)
constexpr int XROW = 24, XPS = 344;        // xh row stride / plane stride (dwords)
constexpr int HR = 14, HC = 22;            // halo extent for 8x16 tile
}

__device__ __forceinline__ unsigned short bf16rne(float f) {
  unsigned u = __float_as_uint(f);
  u += 0x7fffu + ((u >> 16) & 1u);
  return (unsigned short)(u >> 16);
}
__device__ __forceinline__ unsigned packbf2(float a, float b) {
  return (unsigned)bf16rne(a) | ((unsigned)bf16rne(b) << 16);
}

__global__ __launch_bounds__(256, 2) void invol_fused(
    const float* __restrict__ x, const float* __restrict__ w_reduce,
    const float* __restrict__ w_span, const float* __restrict__ bn_gamma,
    const float* __restrict__ bn_beta, const float* __restrict__ bn_mean,
    const float* __restrict__ bn_var, float* __restrict__ out)
{
  __shared__ __align__(16) unsigned short s_rT[TP * LD];   // 18.4 KB, persists
  __shared__ __align__(16) unsigned short s_a [64 * LD];   // 9.2 KB: wr / w_span slice
  __shared__ __align__(16) float s_u[KKn * WLD];           // 25.9 KB: ph1 xT bf16 / ph2 s_w fp32
  __shared__ __align__(16) float s_xh[16 * XPS];           // 22.0 KB: 16 halo planes

  const int t = threadIdx.x;
  const int lane = t & 63, q = t >> 6;
  const int m16 = lane & 15, quad = lane >> 4;
  const int s = lane >> 5;                 // half of wave -> cg split
  const int slot = lane & 31;
  const int py = slot >> 2, px0 = (slot & 3) * 4;
  const int w0 = blockIdx.x * TW, h0 = blockIdx.y * TH;
  const int b = blockIdx.z;
  const long xbase = (long)b * Cn * HWn;

  // BN constants for this lane's phase-1 D rows (o = q*16 + quad*4 + r)
  float bsc[4], bsh[4];
  {
    int ob = q * 16 + quad * 4;
#pragma unroll
    for (int r = 0; r < 4; ++r) {
      float sc = bn_gamma[ob + r] * rsqrtf(bn_var[ob + r] + 1e-5f);
      bsc[r] = sc;
      bsh[r] = bn_beta[ob + r] - bn_mean[ob + r] * sc;
    }
  }

  // ---------------- Phase 1: rT = bf16(ReLU(BN(w_reduce @ x))) ----------------
  f32x4 pac[8];
#pragma unroll
  for (int pt = 0; pt < 8; ++pt) pac[pt] = (f32x4){0.f, 0.f, 0.f, 0.f};

  unsigned short* xT = (unsigned short*)s_u;  // [128 p][72] bf16

  for (int cc = 0; cc < Cn; cc += 64) {
    __syncthreads();
#pragma unroll
    for (int it = 0; it < 8; ++it) {        // s_a = w_reduce[o][cc..] bf16
      int idx = t + it * 256;
      int o = idx >> 5, cp = idx & 31;
      float2 v = *(const float2*)(w_reduce + o * Cn + cc + cp * 2);
      ((unsigned*)s_a)[o * LDW + cp] = packbf2(v.x, v.y);
    }
#pragma unroll
    for (int it = 0; it < 16; ++it) {       // xT[p][c] bf16 (2 ch packed)
      int idx = t + it * 256;
      int pp = idx & 127, cp = idx >> 7;
      const float* gp = x + xbase + (long)(cc + cp * 2) * HWn
                        + (h0 + (pp >> 4)) * Wn + (w0 + (pp & 15));
      ((unsigned*)xT)[pp * LDW + cp] = packbf2(gp[0], gp[HWn]);
    }
    __syncthreads();
#pragma unroll
    for (int ks = 0; ks < 2; ++ks) {
      bf16x8 af = *(const bf16x8*)(s_a + (q * 16 + m16) * LD + ks * 32 + quad * 8);
#pragma unroll
      for (int pt = 0; pt < 8; ++pt) {
        bf16x8 bf = *(const bf16x8*)(xT + (pt * 16 + m16) * LD + ks * 32 + quad * 8);
        pac[pt] = __builtin_amdgcn_mfma_f32_16x16x32_bf16(af, bf, pac[pt], 0, 0, 0);
      }
    }
  }
  // epilogue: BN+ReLU -> rT[p][o] bf16 pairs
#pragma unroll
  for (int pt = 0; pt < 8; ++pt) {
    int pp = pt * 16 + m16;
    float v0 = fmaxf(fmaf(pac[pt][0], bsc[0], bsh[0]), 0.f);
    float v1 = fmaxf(fmaf(pac[pt][1], bsc[1], bsh[1]), 0.f);
    float v2 = fmaxf(fmaf(pac[pt][2], bsc[2], bsh[2]), 0.f);
    float v3 = fmaxf(fmaf(pac[pt][3], bsc[3], bsh[3]), 0.f);
    ((unsigned*)s_rT)[pp * LDW + q * 8 + quad * 2 + 0] = packbf2(v0, v1);
    ((unsigned*)s_rT)[pp * LDW + q * 8 + quad * 2 + 1] = packbf2(v2, v3);
  }

  // ---------------- Phase 2 ----------------
  float* s_w = s_u;                          // [49 k][132] fp32
  const int cgA = q + 4 * s;                 // this lane's 2 cg planes
  const int cgB = cgA + 8;
  const float* plA = s_xh + cgA * XPS;
  const float* plB = s_xh + cgB * XPS;
  const long opix = (h0 + py) * Wn + (w0 + px0);

  for (int g = 0; g < Gn; ++g) {
    __syncthreads();  // prior reads of s_a/s_u/s_xh done
#pragma unroll
    for (int it = 0; it < 8; ++it) {        // s_a = w_span[g] slice [k][o] bf16
      int idx = t + it * 256;
      int k = idx >> 5, op = idx & 31;
      unsigned pv = 0u;
      if (k < KKn) {
        float2 v = *(const float2*)(w_span + (long)(g * KKn + k) * CRn + op * 2);
        pv = packbf2(v.x, v.y);
      }
      ((unsigned*)s_a)[k * LDW + op] = pv;
    }
    for (int idx = t; idx < 16 * 336; idx += 256) {  // 16 halo planes
      int pl = idx / 336, rem = idx - pl * 336;
      int iy = rem / XROW, ix = rem - iy * XROW;     // ix 22,23: harmless pad
      int gy = h0 + iy - PADn, gx = w0 + ix - PADn;
      float v = 0.f;
      if ((unsigned)gy < (unsigned)Hn && (unsigned)gx < (unsigned)Wn)
        v = x[xbase + (long)(g * CGn + pl) * HWn + gy * Wn + gx];
      s_xh[pl * XPS + iy * XROW + ix] = v;
    }
    __syncthreads();

    // kernel-gen: wave q -> k-tile q; D[k][p] = w_span @ r
    f32x4 wac[8];
#pragma unroll
    for (int pt = 0; pt < 8; ++pt) wac[pt] = (f32x4){0.f, 0.f, 0.f, 0.f};
#pragma unroll
    for (int ks = 0; ks < 2; ++ks) {
      bf16x8 af = *(const bf16x8*)(s_a + (q * 16 + m16) * LD + ks * 32 + quad * 8);
#pragma unroll
      for (int pt = 0; pt < 8; ++pt) {
        bf16x8 bf = *(const bf16x8*)(s_rT + (pt * 16 + m16) * LD + ks * 32 + quad * 8);
        wac[pt] = __builtin_amdgcn_mfma_f32_16x16x32_bf16(af, bf, wac[pt], 0, 0, 0);
      }
    }
    {
      int kb = q * 16 + quad * 4;
#pragma unroll
      for (int r = 0; r < 4; ++r) {
        if (kb + r < KKn) {
#pragma unroll
          for (int pt = 0; pt < 8; ++pt)
            s_w[(kb + r) * WLD + pt * 16 + m16] = wac[pt][r];
        }
      }
    }
    __syncthreads();

    // involution: 4 px/lane sliding window, 2 cg planes
    f32x4 a0 = (f32x4){0.f, 0.f, 0.f, 0.f};
    f32x4 a1 = (f32x4){0.f, 0.f, 0.f, 0.f};
#pragma unroll 1
    for (int i = 0; i < Kn; ++i) {
      f32x4 wr_[7];
#pragma unroll
      for (int jx = 0; jx < Kn; ++jx)
        wr_[jx] = *(const f32x4*)(s_w + (i * Kn + jx) * WLD + py * 16 + px0);
      const float* rA = plA + (py + i) * XROW + px0;
      const float* rB = plB + (py + i) * XROW + px0;
      f32x4 xa0 = *(const f32x4*)rA, xa1 = *(const f32x4*)(rA + 4), xa2 = *(const f32x4*)(rA + 8);
      f32x4 xb0 = *(const f32x4*)rB, xb1 = *(const f32x4*)(rB + 4), xb2 = *(const f32x4*)(rB + 8);
      float xa[12] = {xa0[0], xa0[1], xa0[2], xa0[3], xa1[0], xa1[1], xa1[2], xa1[3],
                      xa2[0], xa2[1], xa2[2], xa2[3]};
      float xb[12] = {xb0[0], xb0[1], xb0[2], xb0[3], xb1[0], xb1[1], xb1[2], xb1[3],
                      xb2[0], xb2[1], xb2[2], xb2[3]};
#pragma unroll
      for (int jx = 0; jx < Kn; ++jx) {
#pragma unroll
        for (int j = 0; j < 4; ++j) {
          a0[j] = fmaf(wr_[jx][j], xa[jx + j], a0[j]);
          a1[j] = fmaf(wr_[jx][j], xb[jx + j], a1[j]);
        }
      }
    }
    float* ob = out + xbase + (long)(g * CGn) * HWn + opix;
    *(f32x4*)(ob + (long)cgA * HWn) = a0;
    *(f32x4*)(ob + (long)cgB * HWn) = a1;
  }
}

extern "C" void kernel_launch(void* const* d_in, const int* in_sizes, int n_in,
                              void* d_out, int out_size, void* d_ws, size_t ws_size,
                              hipStream_t stream) {
  const float* x        = (const float*)d_in[0];
  const float* w_reduce = (const float*)d_in[1];
  const float* w_span   = (const float*)d_in[2];
  const float* bn_gamma = (const float*)d_in[3];
  const float* bn_beta  = (const float*)d_in[4];
  const float* bn_mean  = (const float*)d_in[5];
  const float* bn_var   = (const float*)d_in[6];
  float* outp = (float*)d_out;

  dim3 grid(Wn / TW, Hn / TH, 16);  // 4 x 8 x 16 = 512 blocks, 2/CU
  invol_fused<<<grid, 256, 0, stream>>>(x, w_reduce, w_span, bn_gamma,
                                        bn_beta, bn_mean, bn_var, outp);
}